// Round 15
// baseline (58.244 us; speedup 1.0000x reference)
//
#include <hip/hip_runtime.h>
#include <math.h>

#define BB 4
#define CC 64
#define OO 64
#define HH 128
#define WW 128
#define HWsz (HH * WW)
#define PLANE ((size_t)BB * HWsz * 32)   // halfs per channel-plane

typedef __attribute__((ext_vector_type(8))) _Float16 half8;
typedef __attribute__((ext_vector_type(4))) float floatx4;

// ---------------------------------------------------------------------------
// pre: (blocks 0..511)  x NCHW f32 -> xh split-plane NHWC f16:
//        plane0[p*32+q] = ch q (0..31), plane1[p*32+q] = ch 32+q
//      (blocks 512..727) fragment-ordered f16 weight repack:
//  waf[((k*2+kh)*4+m)*512 + lane*8 + j] =
//      f16(wgt[(m*16+(lane&15))*576 + (kh*32+(lane>>4)*8+j)*9 + k])
//  wcf[((k*2+kh)*2+m)*512 + lane*8 + j] = offset(18)/mask(9) rows, 0-padded
// ---------------------------------------------------------------------------
__global__ __launch_bounds__(256) void pre_kernel(
    const float* __restrict__ x, const float* __restrict__ wgt,
    const float* __restrict__ ow, const float* __restrict__ mw,
    _Float16* __restrict__ xh0, _Float16* __restrict__ xh1,
    _Float16* __restrict__ waf, _Float16* __restrict__ wcf)
{
    int bid = blockIdx.x;
    int tid = threadIdx.x;
    if (bid < 512) {
        int b = bid >> 7, y = bid & 127;
        int px = tid & 127;
        int hi = tid >> 7;               // 0: ch 0..31 -> plane0, 1: -> plane1
        const float* xp = x + (size_t)(b * CC + hi * 32) * HWsz + y * WW + px;
        _Float16 buf[32];
#pragma unroll
        for (int q = 0; q < 32; ++q)
            buf[q] = (_Float16)xp[(size_t)q * HWsz];
        _Float16* dst = (hi ? xh1 : xh0)
                      + ((size_t)(b * HH + y) * WW + px) * 32;
#pragma unroll
        for (int q = 0; q < 4; ++q)
            *(half8*)&dst[q * 8] = *(const half8*)&buf[q * 8];
    } else {
        int i = (bid - 512) * 256 + tid;
        if (i < 36864) {
            int j = i & 7, lane = (i >> 3) & 63, rest = i >> 9;
            int m = rest & 3, kh = (rest >> 2) & 1, k = rest >> 3;
            int o = m * 16 + (lane & 15);
            int c = kh * 32 + ((lane >> 4) << 3) + j;
            waf[i] = (_Float16)wgt[o * 576 + c * 9 + k];
        } else if (i < 55296) {
            int t = i - 36864;
            int j = t & 7, lane = (t >> 3) & 63, rest = t >> 9;
            int m = rest & 1, kh = (rest >> 1) & 1, k = rest >> 2;
            int o = m * 16 + (lane & 15);
            int c = kh * 32 + ((lane >> 4) << 3) + j;
            float v = 0.f;
            if (o < 18) v = ow[o * 576 + c * 9 + k];
            else if (o < 27) v = mw[(o - 18) * 576 + c * 9 + k];
            wcf[t] = (_Float16)v;
        }
    }
}

// ---------------------------------------------------------------------------
// fused kernel (fp16, K-split TLP edition).
// 1024 blocks x 512 thr = 8192 waves = 32 waves/CU = 8 waves/SIMD.
// Block: (image b, row h, 64-px col half). 8 waves = 4 strips x 2 khalves.
// Wave (s, khalf): strip s (16 px), channel plane khalf (32 ch).
//   phase 1: offset/mask conv, full K (both planes), wave owns om rows
//            [khalf*16, +16) of its strip; one barrier.
//   phase 2: per tap: 4 corner gathers from ONE plane, blend, 4 weight
//            fragments from global (L1-shared), 4 MFMA (K=32). Depth-0;
//            latency hidden by 8 waves/SIMD.
//   epilogue: khalf=1 partials -> LDS, barrier, khalf=0 adds + writes out.
// ---------------------------------------------------------------------------
__global__ __launch_bounds__(512, 8) void fused_kernel(
    const _Float16* __restrict__ xh0, const _Float16* __restrict__ xh1,
    const _Float16* __restrict__ waf, const _Float16* __restrict__ wcf,
    const float* __restrict__ ob, const float* __restrict__ mb,
    float* __restrict__ out)
{
    __shared__ _Float16 omh[4 * 27 * 16];       //  3456 B
    __shared__ float red[4 * 4 * 64 * 4];       // 16384 B [m][s][lane][4]

    int tid = threadIdx.x;
    int gid = blockIdx.x;
    // XCD-bijective swizzle: 1024 blocks = 8 XCDs x 128 contiguous
    int sid = (gid & 7) * 128 + (gid >> 3);
    int b = sid >> 8;
    int r = sid & 255;
    int h = r >> 1;
    int p0 = (r & 1) << 6;

    int wv = tid >> 6;
    int lane = tid & 63;
    int s = wv & 3;            // strip
    int khalf = wv >> 2;       // channel plane (phase 2) / om-row half (ph 1)
    int g = lane >> 4;
    int pl = lane & 15;
    int goff = g * 8;
    int xw = p0 + s * 16 + pl;

    const _Float16* xp0 = xh0 + (size_t)b * HWsz * 32;
    const _Float16* xp1 = xh1 + (size_t)b * HWsz * 32;
    _Float16* omw = &omh[s * 27 * 16];

    // ---------------- phase 1: offset/mask conv (full K, half rows) --------
    {
        floatx4 accC = {0.f, 0.f, 0.f, 0.f};
#pragma unroll 1
        for (int k = 0; k < 9; ++k) {
            int ky = k / 3, kx = k - ky * 3;
            int yy = h + ky - 1, xx = xw + kx - 1;
            bool valid = (yy >= 0) & (yy < HH) & (xx >= 0) & (xx < WW);
            int yc = min(max(yy, 0), HH - 1), xc = min(max(xx, 0), WW - 1);
            int P = ((yc * WW + xc) << 5) + goff;
            half8 z = {0, 0, 0, 0, 0, 0, 0, 0};
            half8 A0 = valid ? *(const half8*)(xp0 + P) : z;
            half8 A1 = valid ? *(const half8*)(xp1 + P) : z;
            const _Float16* wp = wcf + ((k * 4 + khalf) << 9) + lane * 8;
            half8 w0 = *(const half8*)(wp);
            half8 w1 = *(const half8*)(wp + (2 << 9));
            accC = __builtin_amdgcn_mfma_f32_16x16x32_f16(w0, A0, accC, 0, 0, 0);
            accC = __builtin_amdgcn_mfma_f32_16x16x32_f16(w1, A1, accC, 0, 0, 0);
        }
#pragma unroll
        for (int j = 0; j < 4; ++j) {
            int o = khalf * 16 + g * 4 + j;
            float v = accC[j];
            if (o < 18) omw[o * 16 + pl] = (_Float16)(v + ob[o]);
            else if (o < 27)
                omw[o * 16 + pl] =
                    (_Float16)(1.0f / (1.0f + expf(-(v + mb[o - 18]))));
        }
    }
    __syncthreads();

    // ---------------- phase 2: deformable sampling + GEMM (K-split) -------
    floatx4 acc0 = {0.f, 0.f, 0.f, 0.f}, acc1 = {0.f, 0.f, 0.f, 0.f};
    floatx4 acc2 = {0.f, 0.f, 0.f, 0.f}, acc3 = {0.f, 0.f, 0.f, 0.f};
    {
        const _Float16* xp = khalf ? xp1 : xp0;
#pragma unroll 1
        for (int k = 0; k < 9; ++k) {
            int ky = k / 3, kx = k - ky * 3;
            float oy = (float)omw[(2 * k) * 16 + pl];
            float ox = (float)omw[(2 * k + 1) * 16 + pl];
            float mk = (float)omw[(18 + k) * 16 + pl];
            float py = oy + (float)(h + ky - 1);
            float qx = ox + (float)(xw + kx - 1);
            float y0f = floorf(py), x0f = floorf(qx);
            float dyy = py - y0f, dxx = qx - x0f;
            int y0 = (int)y0f, x0 = (int)x0f;
            int y1 = y0 + 1, x1 = x0 + 1;
            bool vy0 = (y0 >= 0) & (y0 < HH), vy1 = (y1 >= 0) & (y1 < HH);
            bool vx0 = (x0 >= 0) & (x0 < WW), vx1 = (x1 >= 0) & (x1 < WW);
            float u00 = (vy0 & vx0) ? (1.f - dyy) * (1.f - dxx) * mk : 0.f;
            float u01 = (vy0 & vx1) ? (1.f - dyy) * dxx * mk : 0.f;
            float u10 = (vy1 & vx0) ? dyy * (1.f - dxx) * mk : 0.f;
            float u11 = (vy1 & vx1) ? dyy * dxx * mk : 0.f;
            int yc0 = min(max(y0, 0), HH - 1), yc1 = min(max(y1, 0), HH - 1);
            int xc0 = min(max(x0, 0), WW - 1), xc1 = min(max(x1, 0), WW - 1);
            int i00 = ((yc0 * WW + xc0) << 5) + goff;
            int i01 = ((yc0 * WW + xc1) << 5) + goff;
            int i10 = ((yc1 * WW + xc0) << 5) + goff;
            int i11 = ((yc1 * WW + xc1) << 5) + goff;

            half8 c00 = *(const half8*)(xp + i00);
            half8 c01 = *(const half8*)(xp + i01);
            half8 c10 = *(const half8*)(xp + i10);
            half8 c11 = *(const half8*)(xp + i11);

            const _Float16* wk = waf + (((k << 1) + khalf) << 11) + lane * 8;
            half8 q0 = *(const half8*)(wk + (0 << 9));
            half8 q1 = *(const half8*)(wk + (1 << 9));
            half8 q2 = *(const half8*)(wk + (2 << 9));
            half8 q3 = *(const half8*)(wk + (3 << 9));

            _Float16 h00 = (_Float16)u00, h01 = (_Float16)u01;
            _Float16 h10 = (_Float16)u10, h11 = (_Float16)u11;
            half8 U00 = {h00, h00, h00, h00, h00, h00, h00, h00};
            half8 U01 = {h01, h01, h01, h01, h01, h01, h01, h01};
            half8 U10 = {h10, h10, h10, h10, h10, h10, h10, h10};
            half8 U11 = {h11, h11, h11, h11, h11, h11, h11, h11};
            half8 bf = c00 * U00;
            bf = bf + c01 * U01;
            bf = bf + c10 * U10;
            bf = bf + c11 * U11;

            acc0 = __builtin_amdgcn_mfma_f32_16x16x32_f16(q0, bf, acc0, 0, 0, 0);
            acc1 = __builtin_amdgcn_mfma_f32_16x16x32_f16(q1, bf, acc1, 0, 0, 0);
            acc2 = __builtin_amdgcn_mfma_f32_16x16x32_f16(q2, bf, acc2, 0, 0, 0);
            acc3 = __builtin_amdgcn_mfma_f32_16x16x32_f16(q3, bf, acc3, 0, 0, 0);
        }
    }

    // ---------------- cross-wave K-reduction + writeout --------------------
    if (khalf) {
        *(floatx4*)&red[((0 * 4 + s) * 64 + lane) * 4] = acc0;
        *(floatx4*)&red[((1 * 4 + s) * 64 + lane) * 4] = acc1;
        *(floatx4*)&red[((2 * 4 + s) * 64 + lane) * 4] = acc2;
        *(floatx4*)&red[((3 * 4 + s) * 64 + lane) * 4] = acc3;
    }
    __syncthreads();
    if (!khalf) {
        acc0 = acc0 + *(const floatx4*)&red[((0 * 4 + s) * 64 + lane) * 4];
        acc1 = acc1 + *(const floatx4*)&red[((1 * 4 + s) * 64 + lane) * 4];
        acc2 = acc2 + *(const floatx4*)&red[((2 * 4 + s) * 64 + lane) * 4];
        acc3 = acc3 + *(const floatx4*)&red[((3 * 4 + s) * 64 + lane) * 4];
        float* outp = out + (size_t)b * OO * HWsz + h * WW + p0 + s * 16 + pl;
#pragma unroll
        for (int j = 0; j < 4; ++j) outp[(size_t)(g * 4 + j) * HWsz] = acc0[j];
#pragma unroll
        for (int j = 0; j < 4; ++j) outp[(size_t)(16 + g * 4 + j) * HWsz] = acc1[j];
#pragma unroll
        for (int j = 0; j < 4; ++j) outp[(size_t)(32 + g * 4 + j) * HWsz] = acc2[j];
#pragma unroll
        for (int j = 0; j < 4; ++j) outp[(size_t)(48 + g * 4 + j) * HWsz] = acc3[j];
    }
}

extern "C" void kernel_launch(void* const* d_in, const int* in_sizes, int n_in,
                              void* d_out, int out_size, void* d_ws, size_t ws_size,
                              hipStream_t stream)
{
    const float* x   = (const float*)d_in[0];
    const float* ow  = (const float*)d_in[1];
    const float* ob  = (const float*)d_in[2];
    const float* mw  = (const float*)d_in[3];
    const float* mb  = (const float*)d_in[4];
    const float* wgt = (const float*)d_in[5];
    float* out = (float*)d_out;

    // ws: xh0 (4MB) | xh1 (4MB) | waf (36864 f16) | wcf (18432 f16)
    _Float16* xh0 = (_Float16*)d_ws;
    _Float16* xh1 = xh0 + PLANE;
    _Float16* waf = xh1 + PLANE;
    _Float16* wcf = waf + 36864;

    pre_kernel<<<dim3(512 + 216), dim3(256), 0, stream>>>(
        x, wgt, ow, mw, xh0, xh1, waf, wcf);
    fused_kernel<<<dim3(1024), dim3(512), 0, stream>>>(
        xh0, xh1, waf, wcf, ob, mb, out);
}

// Round 16
// 48.793 us; speedup vs baseline: 1.1937x; 1.1937x over previous
//
#include <hip/hip_runtime.h>
#include <math.h>

#define BB 4
#define CC 64
#define OO 64
#define HH 128
#define WW 128
#define HWsz (HH * WW)
#define PLANE ((size_t)BB * HWsz * 32)   // halfs per channel-plane

typedef __attribute__((ext_vector_type(8))) _Float16 half8;
typedef __attribute__((ext_vector_type(4))) float floatx4;

// ---------------------------------------------------------------------------
// pre: (blocks 0..511)  x NCHW f32 -> xh split-plane NHWC f16:
//        plane0[p*32+q] = ch q (0..31), plane1[p*32+q] = ch 32+q
//      (blocks 512..727) fragment-ordered f16 weight repack (as R8):
//  waf[((k*2+kh)*4+m)*512 + lane*8 + j], wcf[((k*2+kh)*2+m)*512 + lane*8 + j]
// ---------------------------------------------------------------------------
__global__ __launch_bounds__(256) void pre_kernel(
    const float* __restrict__ x, const float* __restrict__ wgt,
    const float* __restrict__ ow, const float* __restrict__ mw,
    _Float16* __restrict__ xh0, _Float16* __restrict__ xh1,
    _Float16* __restrict__ waf, _Float16* __restrict__ wcf)
{
    int bid = blockIdx.x;
    int tid = threadIdx.x;
    if (bid < 512) {
        int b = bid >> 7, y = bid & 127;
        int px = tid & 127;
        int hi = tid >> 7;               // 0: ch 0..31 -> plane0, 1: -> plane1
        const float* xp = x + (size_t)(b * CC + hi * 32) * HWsz + y * WW + px;
        _Float16 buf[32];
#pragma unroll
        for (int q = 0; q < 32; ++q)
            buf[q] = (_Float16)xp[(size_t)q * HWsz];
        _Float16* dst = (hi ? xh1 : xh0)
                      + ((size_t)(b * HH + y) * WW + px) * 32;
#pragma unroll
        for (int q = 0; q < 4; ++q)
            *(half8*)&dst[q * 8] = *(const half8*)&buf[q * 8];
    } else {
        int i = (bid - 512) * 256 + tid;
        if (i < 36864) {
            int j = i & 7, lane = (i >> 3) & 63, rest = i >> 9;
            int m = rest & 3, kh = (rest >> 2) & 1, k = rest >> 3;
            int o = m * 16 + (lane & 15);
            int c = kh * 32 + ((lane >> 4) << 3) + j;
            waf[i] = (_Float16)wgt[o * 576 + c * 9 + k];
        } else if (i < 55296) {
            int t = i - 36864;
            int j = t & 7, lane = (t >> 3) & 63, rest = t >> 9;
            int m = rest & 1, kh = (rest >> 1) & 1, k = rest >> 2;
            int o = m * 16 + (lane & 15);
            int c = kh * 32 + ((lane >> 4) << 3) + j;
            float v = 0.f;
            if (o < 18) v = ow[o * 576 + c * 9 + k];
            else if (o < 27) v = mw[(o - 18) * 576 + c * 9 + k];
            wcf[t] = (_Float16)v;
        }
    }
}

// ---------------------------------------------------------------------------
// fused kernel (fp16, split-plane gathers, LDS weights, 8-wave blocks,
// TAP-STAGGERED to break inter-wave convoys).
// 512 blocks x 512 thr; block = full 128-px row; wave = 16-px strip.
// LDS 80640 B -> 2 blocks/CU -> 16 waves/CU (4 waves/SIMD, VGPR cap 128).
// Wave wv visits taps in order (wv, wv+1, ..) mod 9 — commutative sum, so
// result unchanged, but waves sit in different pipeline phases at any time.
// ---------------------------------------------------------------------------
__global__ __launch_bounds__(512, 4) void fused_kernel(
    const _Float16* __restrict__ xh0, const _Float16* __restrict__ xh1,
    const _Float16* __restrict__ waf, const _Float16* __restrict__ wcf,
    const float* __restrict__ ob, const float* __restrict__ mb,
    float* __restrict__ out)
{
    __shared__ __align__(16) _Float16 lds_waf[36864];  // 73728 B
    __shared__ _Float16 omh[8 * 27 * 16];              //  6912 B

    int tid = threadIdx.x;
    int gid = blockIdx.x;
    // XCD-bijective swizzle: 512 blocks = 8 XCDs x 64 contiguous
    int sid = (gid & 7) * 64 + (gid >> 3);
    int b = sid >> 7;
    int h = sid & 127;

    int wv = tid >> 6;        // 0..7: strip index
    int lane = tid & 63;
    int g = lane >> 4;
    int pl = lane & 15;
    int goff = g * 8;
    int xw = wv * 16 + pl;    // this lane's column (full row per block)

    const _Float16* xp0 = xh0 + (size_t)b * HWsz * 32;
    const _Float16* xp1 = xh1 + (size_t)b * HWsz * 32;
    _Float16* omw = &omh[wv * 27 * 16];

    // staggered tap visit order: ks_[i] = (wv + i) mod 9
    int ks_[9];
    ks_[0] = wv;              // wv < 8 < 9
#pragma unroll
    for (int i = 1; i < 9; ++i) ks_[i] = (ks_[i - 1] == 8) ? 0 : ks_[i - 1] + 1;

    // ---- issue weight staging loads into registers (written to LDS later)
    half8 stg[9];
#pragma unroll
    for (int i = 0; i < 9; ++i)
        stg[i] = *(const half8*)(waf + ((wv * 9 + i) << 9) + lane * 8);

    // ---------------- phase 1: offset/mask conv (pipelined, staggered) -----
    floatx4 accC0 = {0.f, 0.f, 0.f, 0.f};
    floatx4 accC1 = {0.f, 0.f, 0.f, 0.f};

#define CADDR(K, P, V) do {                                                  \
    int kk_ = (K);                                                           \
    int ky = kk_ / 3, kx = kk_ - ky * 3;                                     \
    int yy = h + ky - 1, xx = xw + kx - 1;                                   \
    V = (yy >= 0) & (yy < HH) & (xx >= 0) & (xx < WW);                       \
    int yc = min(max(yy, 0), HH - 1), xc = min(max(xx, 0), WW - 1);          \
    P = ((yc * WW + xc) << 5) + goff;                                        \
} while (0)

#define CONVTAP(K, S0, S1, V) do {                                           \
    const _Float16* wp = wcf + ((K) << 11) + lane * 8;                       \
    half8 w00 = *(const half8*)(wp + (0 << 9));                              \
    half8 w01 = *(const half8*)(wp + (1 << 9));                              \
    half8 w10 = *(const half8*)(wp + (2 << 9));                              \
    half8 w11 = *(const half8*)(wp + (3 << 9));                              \
    half8 z = {0, 0, 0, 0, 0, 0, 0, 0};                                     \
    half8 a0 = (V) ? S0 : z;                                                 \
    half8 a1 = (V) ? S1 : z;                                                 \
    accC0 = __builtin_amdgcn_mfma_f32_16x16x32_f16(w00, a0, accC0, 0, 0, 0); \
    accC1 = __builtin_amdgcn_mfma_f32_16x16x32_f16(w01, a0, accC1, 0, 0, 0); \
    accC0 = __builtin_amdgcn_mfma_f32_16x16x32_f16(w10, a1, accC0, 0, 0, 0); \
    accC1 = __builtin_amdgcn_mfma_f32_16x16x32_f16(w11, a1, accC1, 0, 0, 0); \
} while (0)

    {
        bool vA, vB;
        int pa, pb;
        half8 A0, A1, B0, B1;
        CADDR(ks_[0], pa, vA);
        A0 = *(const half8*)(xp0 + pa);
        A1 = *(const half8*)(xp1 + pa);
#pragma unroll
        for (int i = 0; i < 4; ++i) {
            CADDR(ks_[2 * i + 1], pb, vB);
            B0 = *(const half8*)(xp0 + pb);
            B1 = *(const half8*)(xp1 + pb);
            CONVTAP(ks_[2 * i], A0, A1, vA);
            CADDR(ks_[2 * i + 2], pa, vA);
            A0 = *(const half8*)(xp0 + pa);
            A1 = *(const half8*)(xp1 + pa);
            CONVTAP(ks_[2 * i + 1], B0, B1, vB);
        }
        CONVTAP(ks_[8], A0, A1, vA);
    }

    // om epilogue (wave-local, f16)
#pragma unroll
    for (int j = 0; j < 4; ++j) {
        int o = g * 4 + j;
        omw[o * 16 + pl] = (_Float16)(accC0[j] + ob[o]);
        int o2 = 16 + g * 4 + j;
        float v = accC1[j];
        if (o2 < 18) omw[o2 * 16 + pl] = (_Float16)(v + ob[o2]);
        else if (o2 < 27)
            omw[o2 * 16 + pl] =
                (_Float16)(1.0f / (1.0f + expf(-(v + mb[o2 - 18]))));
    }

    // ---- weights reg -> LDS, single barrier
#pragma unroll
    for (int i = 0; i < 9; ++i)
        *(half8*)&lds_waf[((wv * 9 + i) << 9) + lane * 8] = stg[i];
    __syncthreads();

    // ---------------- phase 2: deformable sampling + GEMM (staggered) ------
    floatx4 acc0 = {0.f, 0.f, 0.f, 0.f}, acc1 = {0.f, 0.f, 0.f, 0.f};
    floatx4 acc2 = {0.f, 0.f, 0.f, 0.f}, acc3 = {0.f, 0.f, 0.f, 0.f};

#define MKTAP(K, S) do {                                                     \
    int kk_ = (K);                                                           \
    int ky = kk_ / 3, kx = kk_ - ky * 3;                                     \
    float oy = (float)omw[(2 * kk_) * 16 + pl];                              \
    float ox = (float)omw[(2 * kk_ + 1) * 16 + pl];                          \
    float mk = (float)omw[(18 + kk_) * 16 + pl];                             \
    float py = oy + (float)(h + ky - 1);                                     \
    float qx = ox + (float)(xw + kx - 1);                                    \
    float y0f = floorf(py), x0f = floorf(qx);                                \
    float dyy = py - y0f, dxx = qx - x0f;                                    \
    int y0 = (int)y0f, x0 = (int)x0f;                                        \
    int y1 = y0 + 1, x1 = x0 + 1;                                            \
    bool vy0 = (y0 >= 0) & (y0 < HH), vy1 = (y1 >= 0) & (y1 < HH);           \
    bool vx0 = (x0 >= 0) & (x0 < WW), vx1 = (x1 >= 0) & (x1 < WW);           \
    u00##S = (vy0 & vx0) ? (1.f - dyy) * (1.f - dxx) * mk : 0.f;             \
    u01##S = (vy0 & vx1) ? (1.f - dyy) * dxx * mk : 0.f;                     \
    u10##S = (vy1 & vx0) ? dyy * (1.f - dxx) * mk : 0.f;                     \
    u11##S = (vy1 & vx1) ? dyy * dxx * mk : 0.f;                             \
    int yc0 = min(max(y0, 0), HH - 1), yc1 = min(max(y1, 0), HH - 1);        \
    int xc0 = min(max(x0, 0), WW - 1), xc1 = min(max(x1, 0), WW - 1);        \
    i00##S = ((yc0 * WW + xc0) << 5) + goff;                                 \
    i01##S = ((yc0 * WW + xc1) << 5) + goff;                                 \
    i10##S = ((yc1 * WW + xc0) << 5) + goff;                                 \
    i11##S = ((yc1 * WW + xc1) << 5) + goff;                                 \
} while (0)

#define DECLSET(S)                                                           \
    int i00##S, i01##S, i10##S, i11##S;                                      \
    float u00##S, u01##S, u10##S, u11##S;                                    \
    half8 c00##S, c01##S, c10##S, c11##S, d00##S, d01##S, d10##S, d11##S;

#define PREP(K, S) do {                                                      \
    MKTAP(K, S);                                                             \
    c00##S = *(const half8*)(xp0 + i00##S);                                  \
    c01##S = *(const half8*)(xp0 + i01##S);                                  \
    c10##S = *(const half8*)(xp0 + i10##S);                                  \
    c11##S = *(const half8*)(xp0 + i11##S);                                  \
    d00##S = *(const half8*)(xp1 + i00##S);                                  \
    d01##S = *(const half8*)(xp1 + i01##S);                                  \
    d10##S = *(const half8*)(xp1 + i10##S);                                  \
    d11##S = *(const half8*)(xp1 + i11##S);                                  \
} while (0)

#define SPLAT8(H) ((half8){(H), (H), (H), (H), (H), (H), (H), (H)})
#define MF(Q, B, A) A = __builtin_amdgcn_mfma_f32_16x16x32_f16(Q, B, A, 0, 0, 0)

#define DOTAP(K, S) do {                                                     \
    const _Float16* wk = &lds_waf[((K) << 12) + lane * 8];                   \
    half8 q0 = *(const half8*)(wk + (0 << 9));                               \
    half8 q1 = *(const half8*)(wk + (1 << 9));                               \
    half8 q2 = *(const half8*)(wk + (2 << 9));                               \
    half8 q3 = *(const half8*)(wk + (3 << 9));                               \
    half8 q4 = *(const half8*)(wk + (4 << 9));                               \
    half8 q5 = *(const half8*)(wk + (5 << 9));                               \
    half8 q6 = *(const half8*)(wk + (6 << 9));                               \
    half8 q7 = *(const half8*)(wk + (7 << 9));                               \
    half8 U00 = SPLAT8((_Float16)u00##S), U01 = SPLAT8((_Float16)u01##S);    \
    half8 U10 = SPLAT8((_Float16)u10##S), U11 = SPLAT8((_Float16)u11##S);    \
    half8 bf = c00##S * U00; bf = bf + c01##S * U01;                         \
    bf = bf + c10##S * U10;  bf = bf + c11##S * U11;                         \
    MF(q0, bf, acc0); MF(q1, bf, acc1); MF(q2, bf, acc2); MF(q3, bf, acc3);  \
    half8 bd = d00##S * U00; bd = bd + d01##S * U01;                         \
    bd = bd + d10##S * U10;  bd = bd + d11##S * U11;                         \
    MF(q4, bd, acc0); MF(q5, bd, acc1); MF(q6, bd, acc2); MF(q7, bd, acc3);  \
} while (0)

    {
        DECLSET(A)
        DECLSET(B)
        PREP(ks_[0], A);
        PREP(ks_[1], B);
        DOTAP(ks_[0], A); PREP(ks_[2], A);
        DOTAP(ks_[1], B); PREP(ks_[3], B);
        DOTAP(ks_[2], A); PREP(ks_[4], A);
        DOTAP(ks_[3], B); PREP(ks_[5], B);
        DOTAP(ks_[4], A); PREP(ks_[6], A);
        DOTAP(ks_[5], B); PREP(ks_[7], B);
        DOTAP(ks_[6], A); PREP(ks_[8], A);
        DOTAP(ks_[7], B);
        DOTAP(ks_[8], A);
    }

    // epilogue: D col = pl, row o = m*16 + g*4 + j
    float* outp = out + (size_t)b * OO * HWsz + h * WW + wv * 16 + pl;
#pragma unroll
    for (int j = 0; j < 4; ++j) outp[(size_t)(g * 4 + j) * HWsz] = acc0[j];
#pragma unroll
    for (int j = 0; j < 4; ++j) outp[(size_t)(16 + g * 4 + j) * HWsz] = acc1[j];
#pragma unroll
    for (int j = 0; j < 4; ++j) outp[(size_t)(32 + g * 4 + j) * HWsz] = acc2[j];
#pragma unroll
    for (int j = 0; j < 4; ++j) outp[(size_t)(48 + g * 4 + j) * HWsz] = acc3[j];
}

extern "C" void kernel_launch(void* const* d_in, const int* in_sizes, int n_in,
                              void* d_out, int out_size, void* d_ws, size_t ws_size,
                              hipStream_t stream)
{
    const float* x   = (const float*)d_in[0];
    const float* ow  = (const float*)d_in[1];
    const float* ob  = (const float*)d_in[2];
    const float* mw  = (const float*)d_in[3];
    const float* mb  = (const float*)d_in[4];
    const float* wgt = (const float*)d_in[5];
    float* out = (float*)d_out;

    // ws: xh0 (4MB) | xh1 (4MB) | waf (36864 f16) | wcf (18432 f16)
    _Float16* xh0 = (_Float16*)d_ws;
    _Float16* xh1 = xh0 + PLANE;
    _Float16* waf = xh1 + PLANE;
    _Float16* wcf = waf + 36864;

    pre_kernel<<<dim3(512 + 216), dim3(256), 0, stream>>>(
        x, wgt, ow, mw, xh0, xh1, waf, wcf);
    fused_kernel<<<dim3(512), dim3(512), 0, stream>>>(
        xh0, xh1, waf, wcf, ob, mb, out);
}

// Round 17
// 48.403 us; speedup vs baseline: 1.2033x; 1.0081x over previous
//
#include <hip/hip_runtime.h>
#include <math.h>

#define BB 4
#define CC 64
#define OO 64
#define HH 128
#define WW 128
#define HWsz (HH * WW)
#define PLANE ((size_t)BB * HWsz * 32)   // halfs per channel-plane

typedef __attribute__((ext_vector_type(8))) _Float16 half8;
typedef __attribute__((ext_vector_type(4))) float floatx4;

// ---------------------------------------------------------------------------
// pre: (blocks 0..511)  x NCHW f32 -> xh split-plane NHWC f16:
//        plane0[p*32+q] = ch q (0..31), plane1[p*32+q] = ch 32+q
//      (blocks 512..727) fragment-ordered f16 weight repack (as R8):
//  waf[((k*2+kh)*4+m)*512 + lane*8 + j], wcf[((k*2+kh)*2+m)*512 + lane*8 + j]
// ---------------------------------------------------------------------------
__global__ __launch_bounds__(256) void pre_kernel(
    const float* __restrict__ x, const float* __restrict__ wgt,
    const float* __restrict__ ow, const float* __restrict__ mw,
    _Float16* __restrict__ xh0, _Float16* __restrict__ xh1,
    _Float16* __restrict__ waf, _Float16* __restrict__ wcf)
{
    int bid = blockIdx.x;
    int tid = threadIdx.x;
    if (bid < 512) {
        int b = bid >> 7, y = bid & 127;
        int px = tid & 127;
        int hi = tid >> 7;               // 0: ch 0..31 -> plane0, 1: -> plane1
        const float* xp = x + (size_t)(b * CC + hi * 32) * HWsz + y * WW + px;
        _Float16 buf[32];
#pragma unroll
        for (int q = 0; q < 32; ++q)
            buf[q] = (_Float16)xp[(size_t)q * HWsz];
        _Float16* dst = (hi ? xh1 : xh0)
                      + ((size_t)(b * HH + y) * WW + px) * 32;
#pragma unroll
        for (int q = 0; q < 4; ++q)
            *(half8*)&dst[q * 8] = *(const half8*)&buf[q * 8];
    } else {
        int i = (bid - 512) * 256 + tid;
        if (i < 36864) {
            int j = i & 7, lane = (i >> 3) & 63, rest = i >> 9;
            int m = rest & 3, kh = (rest >> 2) & 1, k = rest >> 3;
            int o = m * 16 + (lane & 15);
            int c = kh * 32 + ((lane >> 4) << 3) + j;
            waf[i] = (_Float16)wgt[o * 576 + c * 9 + k];
        } else if (i < 55296) {
            int t = i - 36864;
            int j = t & 7, lane = (t >> 3) & 63, rest = t >> 9;
            int m = rest & 1, kh = (rest >> 1) & 1, k = rest >> 2;
            int o = m * 16 + (lane & 15);
            int c = kh * 32 + ((lane >> 4) << 3) + j;
            float v = 0.f;
            if (o < 18) v = ow[o * 576 + c * 9 + k];
            else if (o < 27) v = mw[(o - 18) * 576 + c * 9 + k];
            wcf[t] = (_Float16)v;
        }
    }
}

// ---------------------------------------------------------------------------
// fused kernel (fp16, split-plane gathers, LDS weights, L1-LOCALITY BLOCKS).
// 256 blocks x 1024 thr = 1 block/CU; 16 waves = 4 rows x 4 strips over a
// 64-px column half. The block's gather region (~6 rows x 64 px) is shared
// by all 16 waves in ONE L1, instead of 2 disjoint-row blocks thrashing it.
//   entry:   waves 0-7 stage waf->reg (9 frags each; hide under phase 1)
//   phase 1: offset/mask conv (pair-pipelined) -> om (f16, wave-local LDS)
//   stage:   reg -> LDS weights, one __syncthreads
//   phase 2: depth-1 two-set rotation, compiler-scheduled (R14 code).
// ---------------------------------------------------------------------------
__global__ __launch_bounds__(1024, 1) void fused_kernel(
    const _Float16* __restrict__ xh0, const _Float16* __restrict__ xh1,
    const _Float16* __restrict__ waf, const _Float16* __restrict__ wcf,
    const float* __restrict__ ob, const float* __restrict__ mb,
    float* __restrict__ out)
{
    __shared__ __align__(16) _Float16 lds_waf[36864];  // 73728 B
    __shared__ _Float16 omh[16 * 27 * 16];             // 13824 B

    int tid = threadIdx.x;
    int gid = blockIdx.x;
    // XCD swizzle: 256 blocks = 8 XCDs x 32 contiguous region-tiles
    int sid = (gid & 7) * 32 + (gid >> 3);
    int b = sid >> 6;          // image
    int t = sid & 63;
    int rq = t >> 1;           // row quad 0..31
    int q = t & 1;             // column half

    int wv = tid >> 6;         // 0..15
    int lane = tid & 63;
    int s = wv & 3;            // strip within 64-px half
    int h = rq * 4 + (wv >> 2);
    int p0 = q << 6;
    int g = lane >> 4;
    int pl = lane & 15;
    int goff = g * 8;
    int xw = p0 + s * 16 + pl;

    const _Float16* xp0 = xh0 + (size_t)b * HWsz * 32;
    const _Float16* xp1 = xh1 + (size_t)b * HWsz * 32;
    _Float16* omw = &omh[wv * 27 * 16];

    // ---- waves 0-7: issue weight staging loads (written to LDS later)
    half8 stg[9];
    if (wv < 8) {
#pragma unroll
        for (int i = 0; i < 9; ++i)
            stg[i] = *(const half8*)(waf + ((wv * 9 + i) << 9) + lane * 8);
    }

    // ---------------- phase 1: offset/mask conv (pipelined, f16) -----------
    floatx4 accC0 = {0.f, 0.f, 0.f, 0.f};
    floatx4 accC1 = {0.f, 0.f, 0.f, 0.f};

#define CADDR(K, P, V) do {                                                  \
    int ky = (K) / 3, kx = (K) - ky * 3;                                     \
    int yy = h + ky - 1, xx = xw + kx - 1;                                   \
    V = (yy >= 0) & (yy < HH) & (xx >= 0) & (xx < WW);                       \
    int yc = min(max(yy, 0), HH - 1), xc = min(max(xx, 0), WW - 1);          \
    P = ((yc * WW + xc) << 5) + goff;                                        \
} while (0)

#define CONVTAP(K, S0, S1, V) do {                                           \
    const _Float16* wp = wcf + ((K) << 11) + lane * 8;                       \
    half8 w00 = *(const half8*)(wp + (0 << 9));                              \
    half8 w01 = *(const half8*)(wp + (1 << 9));                              \
    half8 w10 = *(const half8*)(wp + (2 << 9));                              \
    half8 w11 = *(const half8*)(wp + (3 << 9));                              \
    half8 z = {0, 0, 0, 0, 0, 0, 0, 0};                                     \
    half8 a0 = (V) ? S0 : z;                                                 \
    half8 a1 = (V) ? S1 : z;                                                 \
    accC0 = __builtin_amdgcn_mfma_f32_16x16x32_f16(w00, a0, accC0, 0, 0, 0); \
    accC1 = __builtin_amdgcn_mfma_f32_16x16x32_f16(w01, a0, accC1, 0, 0, 0); \
    accC0 = __builtin_amdgcn_mfma_f32_16x16x32_f16(w10, a1, accC0, 0, 0, 0); \
    accC1 = __builtin_amdgcn_mfma_f32_16x16x32_f16(w11, a1, accC1, 0, 0, 0); \
} while (0)

    {
        bool vA, vB;
        int pa, pb;
        half8 A0, A1, B0, B1;
        CADDR(0, pa, vA);
        A0 = *(const half8*)(xp0 + pa);
        A1 = *(const half8*)(xp1 + pa);
#pragma unroll 1
        for (int kp = 0; kp < 4; ++kp) {
            int k = kp * 2;
            CADDR(k + 1, pb, vB);
            B0 = *(const half8*)(xp0 + pb);
            B1 = *(const half8*)(xp1 + pb);
            CONVTAP(k, A0, A1, vA);
            CADDR(k + 2, pa, vA);
            A0 = *(const half8*)(xp0 + pa);
            A1 = *(const half8*)(xp1 + pa);
            CONVTAP(k + 1, B0, B1, vB);
        }
        CONVTAP(8, A0, A1, vA);
    }

    // om epilogue (wave-local, f16)
#pragma unroll
    for (int j = 0; j < 4; ++j) {
        int o = g * 4 + j;
        omw[o * 16 + pl] = (_Float16)(accC0[j] + ob[o]);
        int o2 = 16 + g * 4 + j;
        float v = accC1[j];
        if (o2 < 18) omw[o2 * 16 + pl] = (_Float16)(v + ob[o2]);
        else if (o2 < 27)
            omw[o2 * 16 + pl] =
                (_Float16)(1.0f / (1.0f + expf(-(v + mb[o2 - 18]))));
    }

    // ---- weights reg -> LDS (waves 0-7), single barrier
    if (wv < 8) {
#pragma unroll
        for (int i = 0; i < 9; ++i)
            *(half8*)&lds_waf[((wv * 9 + i) << 9) + lane * 8] = stg[i];
    }
    __syncthreads();

    // ---------------- phase 2: deformable sampling + GEMM ------------------
    floatx4 acc0 = {0.f, 0.f, 0.f, 0.f}, acc1 = {0.f, 0.f, 0.f, 0.f};
    floatx4 acc2 = {0.f, 0.f, 0.f, 0.f}, acc3 = {0.f, 0.f, 0.f, 0.f};

#define MKTAP(K, S) do {                                                     \
    int ky = (K) / 3, kx = (K) - ky * 3;                                     \
    float oy = (float)omw[(2 * (K)) * 16 + pl];                              \
    float ox = (float)omw[(2 * (K) + 1) * 16 + pl];                          \
    float mk = (float)omw[(18 + (K)) * 16 + pl];                             \
    float py = oy + (float)(h + ky - 1);                                     \
    float qx = ox + (float)(xw + kx - 1);                                    \
    float y0f = floorf(py), x0f = floorf(qx);                                \
    float dyy = py - y0f, dxx = qx - x0f;                                    \
    int y0 = (int)y0f, x0 = (int)x0f;                                        \
    int y1 = y0 + 1, x1 = x0 + 1;                                            \
    bool vy0 = (y0 >= 0) & (y0 < HH), vy1 = (y1 >= 0) & (y1 < HH);           \
    bool vx0 = (x0 >= 0) & (x0 < WW), vx1 = (x1 >= 0) & (x1 < WW);           \
    u00##S = (vy0 & vx0) ? (1.f - dyy) * (1.f - dxx) * mk : 0.f;             \
    u01##S = (vy0 & vx1) ? (1.f - dyy) * dxx * mk : 0.f;                     \
    u10##S = (vy1 & vx0) ? dyy * (1.f - dxx) * mk : 0.f;                     \
    u11##S = (vy1 & vx1) ? dyy * dxx * mk : 0.f;                             \
    int yc0 = min(max(y0, 0), HH - 1), yc1 = min(max(y1, 0), HH - 1);        \
    int xc0 = min(max(x0, 0), WW - 1), xc1 = min(max(x1, 0), WW - 1);        \
    i00##S = ((yc0 * WW + xc0) << 5) + goff;                                 \
    i01##S = ((yc0 * WW + xc1) << 5) + goff;                                 \
    i10##S = ((yc1 * WW + xc0) << 5) + goff;                                 \
    i11##S = ((yc1 * WW + xc1) << 5) + goff;                                 \
} while (0)

#define DECLSET(S)                                                           \
    int i00##S, i01##S, i10##S, i11##S;                                      \
    float u00##S, u01##S, u10##S, u11##S;                                    \
    half8 c00##S, c01##S, c10##S, c11##S, d00##S, d01##S, d10##S, d11##S;

#define PREP(K, S) do {                                                      \
    MKTAP(K, S);                                                             \
    c00##S = *(const half8*)(xp0 + i00##S);                                  \
    c01##S = *(const half8*)(xp0 + i01##S);                                  \
    c10##S = *(const half8*)(xp0 + i10##S);                                  \
    c11##S = *(const half8*)(xp0 + i11##S);                                  \
    d00##S = *(const half8*)(xp1 + i00##S);                                  \
    d01##S = *(const half8*)(xp1 + i01##S);                                  \
    d10##S = *(const half8*)(xp1 + i10##S);                                  \
    d11##S = *(const half8*)(xp1 + i11##S);                                  \
} while (0)

#define SPLAT8(H) ((half8){(H), (H), (H), (H), (H), (H), (H), (H)})
#define MF(Q, B, A) A = __builtin_amdgcn_mfma_f32_16x16x32_f16(Q, B, A, 0, 0, 0)

#define DOTAP(K, S) do {                                                     \
    const _Float16* wk = &lds_waf[((K) << 12) + lane * 8];                   \
    half8 q0 = *(const half8*)(wk + (0 << 9));                               \
    half8 q1 = *(const half8*)(wk + (1 << 9));                               \
    half8 q2 = *(const half8*)(wk + (2 << 9));                               \
    half8 q3 = *(const half8*)(wk + (3 << 9));                               \
    half8 q4 = *(const half8*)(wk + (4 << 9));                               \
    half8 q5 = *(const half8*)(wk + (5 << 9));                               \
    half8 q6 = *(const half8*)(wk + (6 << 9));                               \
    half8 q7 = *(const half8*)(wk + (7 << 9));                               \
    half8 U00 = SPLAT8((_Float16)u00##S), U01 = SPLAT8((_Float16)u01##S);    \
    half8 U10 = SPLAT8((_Float16)u10##S), U11 = SPLAT8((_Float16)u11##S);    \
    half8 bf = c00##S * U00; bf = bf + c01##S * U01;                         \
    bf = bf + c10##S * U10;  bf = bf + c11##S * U11;                         \
    MF(q0, bf, acc0); MF(q1, bf, acc1); MF(q2, bf, acc2); MF(q3, bf, acc3);  \
    half8 bd = d00##S * U00; bd = bd + d01##S * U01;                         \
    bd = bd + d10##S * U10;  bd = bd + d11##S * U11;                         \
    MF(q4, bd, acc0); MF(q5, bd, acc1); MF(q6, bd, acc2); MF(q7, bd, acc3);  \
} while (0)

    {
        DECLSET(A)
        DECLSET(B)
        PREP(0, A);
        PREP(1, B);
        DOTAP(0, A); PREP(2, A);
        DOTAP(1, B); PREP(3, B);
        DOTAP(2, A); PREP(4, A);
        DOTAP(3, B); PREP(5, B);
        DOTAP(4, A); PREP(6, A);
        DOTAP(5, B); PREP(7, B);
        DOTAP(6, A); PREP(8, A);
        DOTAP(7, B);
        DOTAP(8, A);
    }

    // epilogue: D col = pl, row o = m*16 + g*4 + j
    float* outp = out + (size_t)b * OO * HWsz + h * WW + p0 + s * 16 + pl;
#pragma unroll
    for (int j = 0; j < 4; ++j) outp[(size_t)(g * 4 + j) * HWsz] = acc0[j];
#pragma unroll
    for (int j = 0; j < 4; ++j) outp[(size_t)(16 + g * 4 + j) * HWsz] = acc1[j];
#pragma unroll
    for (int j = 0; j < 4; ++j) outp[(size_t)(32 + g * 4 + j) * HWsz] = acc2[j];
#pragma unroll
    for (int j = 0; j < 4; ++j) outp[(size_t)(48 + g * 4 + j) * HWsz] = acc3[j];
}

extern "C" void kernel_launch(void* const* d_in, const int* in_sizes, int n_in,
                              void* d_out, int out_size, void* d_ws, size_t ws_size,
                              hipStream_t stream)
{
    const float* x   = (const float*)d_in[0];
    const float* ow  = (const float*)d_in[1];
    const float* ob  = (const float*)d_in[2];
    const float* mw  = (const float*)d_in[3];
    const float* mb  = (const float*)d_in[4];
    const float* wgt = (const float*)d_in[5];
    float* out = (float*)d_out;

    // ws: xh0 (4MB) | xh1 (4MB) | waf (36864 f16) | wcf (18432 f16)
    _Float16* xh0 = (_Float16*)d_ws;
    _Float16* xh1 = xh0 + PLANE;
    _Float16* waf = xh1 + PLANE;
    _Float16* wcf = waf + 36864;

    pre_kernel<<<dim3(512 + 216), dim3(256), 0, stream>>>(
        x, wgt, ow, mw, xh0, xh1, waf, wcf);
    fused_kernel<<<dim3(256), dim3(1024), 0, stream>>>(
        xh0, xh1, waf, wcf, ob, mb, out);
}

// Round 18
// 44.299 us; speedup vs baseline: 1.3148x; 1.0926x over previous
//
#include <hip/hip_runtime.h>
#include <math.h>

#define BB 4
#define CC 64
#define OO 64
#define HH 128
#define WW 128
#define HWsz (HH * WW)

typedef __attribute__((ext_vector_type(8))) _Float16 half8;
typedef __attribute__((ext_vector_type(4))) float floatx4;

// ---------------------------------------------------------------------------
// pre: (blocks 0..511)  x NCHW f32 -> xh merged NHWC f16 (px = 128B = 1 line)
//      (blocks 512..727) fragment-ordered f16 weight repack:
//  waf[((k*2+kh)*4+m)*512 + lane*8 + j], wcf[((k*2+kh)*2+m)*512 + lane*8 + j]
// ---------------------------------------------------------------------------
__global__ __launch_bounds__(256) void pre_kernel(
    const float* __restrict__ x, const float* __restrict__ wgt,
    const float* __restrict__ ow, const float* __restrict__ mw,
    _Float16* __restrict__ xh, _Float16* __restrict__ waf,
    _Float16* __restrict__ wcf)
{
    int bid = blockIdx.x;
    int tid = threadIdx.x;
    if (bid < 512) {
        int b = bid >> 7, y = bid & 127;
        int px = tid & 127;
        int ch = (tid >> 7) * 32;
        const float* xp = x + (size_t)(b * CC + ch) * HWsz + y * WW + px;
        _Float16 buf[32];
#pragma unroll
        for (int q = 0; q < 32; ++q)
            buf[q] = (_Float16)xp[(size_t)q * HWsz];
        _Float16* dst = xh + ((size_t)(b * HH + y) * WW + px) * 64 + ch;
#pragma unroll
        for (int q = 0; q < 4; ++q)
            *(half8*)&dst[q * 8] = *(const half8*)&buf[q * 8];
    } else {
        int i = (bid - 512) * 256 + tid;
        if (i < 36864) {
            int j = i & 7, lane = (i >> 3) & 63, rest = i >> 9;
            int m = rest & 3, kh = (rest >> 2) & 1, k = rest >> 3;
            int o = m * 16 + (lane & 15);
            int c = kh * 32 + ((lane >> 4) << 3) + j;
            waf[i] = (_Float16)wgt[o * 576 + c * 9 + k];
        } else if (i < 55296) {
            int t = i - 36864;
            int j = t & 7, lane = (t >> 3) & 63, rest = t >> 9;
            int m = rest & 1, kh = (rest >> 1) & 1, k = rest >> 2;
            int o = m * 16 + (lane & 15);
            int c = kh * 32 + ((lane >> 4) << 3) + j;
            float v = 0.f;
            if (o < 18) v = ow[o * 576 + c * 9 + k];
            else if (o < 27) v = mw[(o - 18) * 576 + c * 9 + k];
            wcf[t] = (_Float16)v;
        }
    }
}

// ---------------------------------------------------------------------------
// fused kernel (fp16, FULL-LINE gathers + wave-private LDS bounce).
// 256 blocks x 1024 thr = 1 block/CU, 16 waves = 4 rows x 4 strips x 64-px
// column half. Phase 2: 8 lanes per pixel fetch the pixel's FULL 128B line
// (1 L1 line-visit per px-corner, vs ~2 half-used before); bilinear blend in
// gather layout; redistribute blended result to MFMA fragment layout via a
// wave-private swizzled 2KB LDS tile (no barriers).
// ---------------------------------------------------------------------------
__global__ __launch_bounds__(1024, 1) void fused_kernel(
    const _Float16* __restrict__ xh, const _Float16* __restrict__ waf,
    const _Float16* __restrict__ wcf, const float* __restrict__ ob,
    const float* __restrict__ mb, float* __restrict__ out)
{
    __shared__ __align__(16) _Float16 lds_waf[36864];     // 73728 B
    __shared__ _Float16 omh[16 * 27 * 16];                // 13824 B
    __shared__ __align__(16) _Float16 blendb[16 * 2048];  // 65536 B

    int tid = threadIdx.x;
    int gid = blockIdx.x;
    // XCD swizzle: 256 blocks = 8 XCDs x 32 contiguous region-tiles
    int sid = (gid & 7) * 32 + (gid >> 3);
    int b = sid >> 6;
    int t = sid & 63;
    int rq = t >> 1;
    int q = t & 1;

    int wv = tid >> 6;         // 0..15
    int lane = tid & 63;
    int s = wv & 3;            // strip
    int h = rq * 4 + (wv >> 2);
    int p0 = q << 6;
    int g = lane >> 4;
    int pl = lane & 15;
    int goff = g * 8;
    int xw = p0 + s * 16 + pl;
    int oct = lane & 7;        // phase-2 gather: channel octet
    int pxg = lane >> 3;       // phase-2 gather: pixel within 8-px group

    const _Float16* xhb = xh + ((size_t)b << 20);
    _Float16* omw = &omh[wv * 27 * 16];
    _Float16* bbw = &blendb[wv * 2048];

    // ---- waves 0-7: issue weight staging loads (written to LDS later)
    half8 stg[9];
    if (wv < 8) {
#pragma unroll
        for (int i = 0; i < 9; ++i)
            stg[i] = *(const half8*)(waf + ((wv * 9 + i) << 9) + lane * 8);
    }

    // ---------------- phase 1: offset/mask conv (pipelined, f16) -----------
    floatx4 accC0 = {0.f, 0.f, 0.f, 0.f};
    floatx4 accC1 = {0.f, 0.f, 0.f, 0.f};

#define CADDR(K, P, V) do {                                                  \
    int ky = (K) / 3, kx = (K) - ky * 3;                                     \
    int yy = h + ky - 1, xx = xw + kx - 1;                                   \
    V = (yy >= 0) & (yy < HH) & (xx >= 0) & (xx < WW);                       \
    int yc = min(max(yy, 0), HH - 1), xc = min(max(xx, 0), WW - 1);          \
    P = ((yc * WW + xc) << 6) + goff;                                        \
} while (0)

#define CONVTAP(K, S0, S1, V) do {                                           \
    const _Float16* wp = wcf + ((K) << 11) + lane * 8;                       \
    half8 w00 = *(const half8*)(wp + (0 << 9));                              \
    half8 w01 = *(const half8*)(wp + (1 << 9));                              \
    half8 w10 = *(const half8*)(wp + (2 << 9));                              \
    half8 w11 = *(const half8*)(wp + (3 << 9));                              \
    half8 z = {0, 0, 0, 0, 0, 0, 0, 0};                                     \
    half8 a0 = (V) ? S0 : z;                                                 \
    half8 a1 = (V) ? S1 : z;                                                 \
    accC0 = __builtin_amdgcn_mfma_f32_16x16x32_f16(w00, a0, accC0, 0, 0, 0); \
    accC1 = __builtin_amdgcn_mfma_f32_16x16x32_f16(w01, a0, accC1, 0, 0, 0); \
    accC0 = __builtin_amdgcn_mfma_f32_16x16x32_f16(w10, a1, accC0, 0, 0, 0); \
    accC1 = __builtin_amdgcn_mfma_f32_16x16x32_f16(w11, a1, accC1, 0, 0, 0); \
} while (0)

    {
        bool vA, vB;
        int pa, pb;
        half8 A0, A1, B0, B1;
        CADDR(0, pa, vA);
        A0 = *(const half8*)(xhb + pa);
        A1 = *(const half8*)(xhb + pa + 32);
#pragma unroll 1
        for (int kp = 0; kp < 4; ++kp) {
            int k = kp * 2;
            CADDR(k + 1, pb, vB);
            B0 = *(const half8*)(xhb + pb);
            B1 = *(const half8*)(xhb + pb + 32);
            CONVTAP(k, A0, A1, vA);
            CADDR(k + 2, pa, vA);
            A0 = *(const half8*)(xhb + pa);
            A1 = *(const half8*)(xhb + pa + 32);
            CONVTAP(k + 1, B0, B1, vB);
        }
        CONVTAP(8, A0, A1, vA);
    }

    // om epilogue (wave-local, f16)
#pragma unroll
    for (int j = 0; j < 4; ++j) {
        int o = g * 4 + j;
        omw[o * 16 + pl] = (_Float16)(accC0[j] + ob[o]);
        int o2 = 16 + g * 4 + j;
        float v = accC1[j];
        if (o2 < 18) omw[o2 * 16 + pl] = (_Float16)(v + ob[o2]);
        else if (o2 < 27)
            omw[o2 * 16 + pl] =
                (_Float16)(1.0f / (1.0f + expf(-(v + mb[o2 - 18]))));
    }

    // ---- weights reg -> LDS (waves 0-7), single barrier
    if (wv < 8) {
#pragma unroll
        for (int i = 0; i < 9; ++i)
            *(half8*)&lds_waf[((wv * 9 + i) << 9) + lane * 8] = stg[i];
    }
    __syncthreads();

    // ---------------- phase 2: full-line gathers + LDS bounce + GEMM -------
    floatx4 acc0 = {0.f, 0.f, 0.f, 0.f}, acc1 = {0.f, 0.f, 0.f, 0.f};
    floatx4 acc2 = {0.f, 0.f, 0.f, 0.f}, acc3 = {0.f, 0.f, 0.f, 0.f};

// tap params for pixel P (0..15 in strip); this lane's channel octet `oct`
#define MKT(K, P, U00, U01, U10, U11, I00, I01, I10, I11) do {               \
    int ky = (K) / 3, kx = (K) - ky * 3;                                     \
    float oy = (float)omw[(2 * (K)) * 16 + (P)];                             \
    float ox = (float)omw[(2 * (K) + 1) * 16 + (P)];                         \
    float mk = (float)omw[(18 + (K)) * 16 + (P)];                            \
    float py = oy + (float)(h + ky - 1);                                     \
    float qx = ox + (float)(p0 + s * 16 + (P) + kx - 1);                     \
    float y0f = floorf(py), x0f = floorf(qx);                                \
    float dyy = py - y0f, dxx = qx - x0f;                                    \
    int y0 = (int)y0f, x0 = (int)x0f;                                        \
    int y1 = y0 + 1, x1 = x0 + 1;                                            \
    bool vy0 = (y0 >= 0) & (y0 < HH), vy1 = (y1 >= 0) & (y1 < HH);           \
    bool vx0 = (x0 >= 0) & (x0 < WW), vx1 = (x1 >= 0) & (x1 < WW);           \
    U00 = (vy0 & vx0) ? (1.f - dyy) * (1.f - dxx) * mk : 0.f;                \
    U01 = (vy0 & vx1) ? (1.f - dyy) * dxx * mk : 0.f;                        \
    U10 = (vy1 & vx0) ? dyy * (1.f - dxx) * mk : 0.f;                        \
    U11 = (vy1 & vx1) ? dyy * dxx * mk : 0.f;                                \
    int yc0 = min(max(y0, 0), HH - 1), yc1 = min(max(y1, 0), HH - 1);        \
    int xc0 = min(max(x0, 0), WW - 1), xc1 = min(max(x1, 0), WW - 1);        \
    I00 = ((yc0 * WW + xc0) << 6) + oct * 8;                                 \
    I01 = ((yc0 * WW + xc1) << 6) + oct * 8;                                 \
    I10 = ((yc1 * WW + xc0) << 6) + oct * 8;                                 \
    I11 = ((yc1 * WW + xc1) << 6) + oct * 8;                                 \
} while (0)

#define SPLAT8(H) ((half8){(H), (H), (H), (H), (H), (H), (H), (H)})
#define MF(Q, B, A) A = __builtin_amdgcn_mfma_f32_16x16x32_f16(Q, B, A, 0, 0, 0)

#define TAP(K) do {                                                          \
    float uA0, uA1, uA2, uA3, uB0, uB1, uB2, uB3;                            \
    int iA0, iA1, iA2, iA3, iB0, iB1, iB2, iB3;                              \
    MKT(K, pxg, uA0, uA1, uA2, uA3, iA0, iA1, iA2, iA3);                     \
    MKT(K, 8 + pxg, uB0, uB1, uB2, uB3, iB0, iB1, iB2, iB3);                 \
    half8 a0 = *(const half8*)(xhb + iA0);                                   \
    half8 a1 = *(const half8*)(xhb + iA1);                                   \
    half8 a2 = *(const half8*)(xhb + iA2);                                   \
    half8 a3 = *(const half8*)(xhb + iA3);                                   \
    half8 e0 = *(const half8*)(xhb + iB0);                                   \
    half8 e1 = *(const half8*)(xhb + iB1);                                   \
    half8 e2 = *(const half8*)(xhb + iB2);                                   \
    half8 e3 = *(const half8*)(xhb + iB3);                                   \
    half8 bfA = a0 * SPLAT8((_Float16)uA0);                                  \
    bfA = bfA + a1 * SPLAT8((_Float16)uA1);                                  \
    bfA = bfA + a2 * SPLAT8((_Float16)uA2);                                  \
    bfA = bfA + a3 * SPLAT8((_Float16)uA3);                                  \
    half8 bfB = e0 * SPLAT8((_Float16)uB0);                                  \
    bfB = bfB + e1 * SPLAT8((_Float16)uB1);                                  \
    bfB = bfB + e2 * SPLAT8((_Float16)uB2);                                  \
    bfB = bfB + e3 * SPLAT8((_Float16)uB3);                                  \
    _Float16* bb = bbw + (((K) & 1) << 10);                                  \
    *(half8*)&bb[(pxg << 6) + ((oct ^ pxg) << 3)] = bfA;                     \
    *(half8*)&bb[((8 + pxg) << 6) + ((oct ^ pxg) << 3)] = bfB;               \
    half8 bf = *(const half8*)&bb[(pl << 6) + ((g ^ (pl & 7)) << 3)];        \
    half8 bd = *(const half8*)&bb[(pl << 6) + (((g + 4) ^ (pl & 7)) << 3)];  \
    const _Float16* wk = &lds_waf[((K) << 12) + lane * 8];                   \
    half8 q0 = *(const half8*)(wk + (0 << 9));                               \
    half8 q1 = *(const half8*)(wk + (1 << 9));                               \
    half8 q2 = *(const half8*)(wk + (2 << 9));                               \
    half8 q3 = *(const half8*)(wk + (3 << 9));                               \
    half8 q4 = *(const half8*)(wk + (4 << 9));                               \
    half8 q5 = *(const half8*)(wk + (5 << 9));                               \
    half8 q6 = *(const half8*)(wk + (6 << 9));                               \
    half8 q7 = *(const half8*)(wk + (7 << 9));                               \
    MF(q0, bf, acc0); MF(q1, bf, acc1); MF(q2, bf, acc2); MF(q3, bf, acc3);  \
    MF(q4, bd, acc0); MF(q5, bd, acc1); MF(q6, bd, acc2); MF(q7, bd, acc3);  \
} while (0)

    TAP(0); TAP(1); TAP(2); TAP(3); TAP(4); TAP(5); TAP(6); TAP(7); TAP(8);

    // epilogue: D col = pl, row o = m*16 + g*4 + j
    float* outp = out + (size_t)b * OO * HWsz + h * WW + p0 + s * 16 + pl;
#pragma unroll
    for (int j = 0; j < 4; ++j) outp[(size_t)(g * 4 + j) * HWsz] = acc0[j];
#pragma unroll
    for (int j = 0; j < 4; ++j) outp[(size_t)(16 + g * 4 + j) * HWsz] = acc1[j];
#pragma unroll
    for (int j = 0; j < 4; ++j) outp[(size_t)(32 + g * 4 + j) * HWsz] = acc2[j];
#pragma unroll
    for (int j = 0; j < 4; ++j) outp[(size_t)(48 + g * 4 + j) * HWsz] = acc3[j];
}

extern "C" void kernel_launch(void* const* d_in, const int* in_sizes, int n_in,
                              void* d_out, int out_size, void* d_ws, size_t ws_size,
                              hipStream_t stream)
{
    const float* x   = (const float*)d_in[0];
    const float* ow  = (const float*)d_in[1];
    const float* ob  = (const float*)d_in[2];
    const float* mw  = (const float*)d_in[3];
    const float* mb  = (const float*)d_in[4];
    const float* wgt = (const float*)d_in[5];
    float* out = (float*)d_out;

    // ws: xh (4*16384*64 f16 = 8.39MB) | waf (36864 f16) | wcf (18432 f16)
    _Float16* xh  = (_Float16*)d_ws;
    _Float16* waf = xh + (size_t)BB * HWsz * 64;
    _Float16* wcf = waf + 36864;

    pre_kernel<<<dim3(512 + 216), dim3(256), 0, stream>>>(
        x, wgt, ow, mw, xh, waf, wcf);
    fused_kernel<<<dim3(256), dim3(1024), 0, stream>>>(
        xh, waf, wcf, ob, mb, out);
}